// Round 1
// baseline (2310.247 us; speedup 1.0000x reference)
//
#include <hip/hip_runtime.h>

typedef unsigned short u16;
typedef __attribute__((ext_vector_type(4))) float f32x4;
typedef __attribute__((ext_vector_type(8))) short s16x8;

#define GM 262144   // B*N rows
#define GB 64
#define GN 4096
#define GC 256
#define GD 256
#define GS 8
#define GH 512

__device__ __forceinline__ float bf2f(u16 u) {
  union { unsigned int i; float f; } c; c.i = ((unsigned int)u) << 16; return c.f;
}
__device__ __forceinline__ u16 f2bf(float f) {
  union { float f; unsigned int i; } c; c.f = f;
  unsigned int x = c.i;
  unsigned int r = x + 0x7FFFu + ((x >> 16) & 1u);
  return (u16)(r >> 16);
}

// ---------------- slots init: mu + exp(log_sigma)*noise ----------------
__global__ void init_slots_kernel(const float* __restrict__ noise, const float* __restrict__ smu,
                                  const float* __restrict__ sls, float* __restrict__ slots)
{
  int i = blockIdx.x * 256 + threadIdx.x;   // 131072 total
  int d = i & 255;
  slots[i] = smu[d] + expf(sls[d]) * noise[i];
}

// ---------------- per-row LN stats of inputs ----------------
__global__ __launch_bounds__(256) void ln_stats_kernel(const float* __restrict__ x, float2* __restrict__ murstd)
{
  int row = blockIdx.x * 4 + (threadIdx.x >> 6);
  int lane = threadIdx.x & 63;
  f32x4 v = *(const f32x4*)&x[(size_t)row * 256 + lane * 4];
  float s = v.x + v.y + v.z + v.w;
  float sq = v.x*v.x + v.y*v.y + v.z*v.z + v.w*v.w;
  #pragma unroll
  for (int m = 1; m < 64; m <<= 1) { s += __shfl_xor(s, m, 64); sq += __shfl_xor(sq, m, 64); }
  if (lane == 0) {
    float mu = s * (1.f/256.f);
    float var = sq * (1.f/256.f) - mu*mu;
    murstd[row] = make_float2(mu, rsqrtf(var + 1e-3f));
  }
}

// ---------------- weight convert fp32->bf16 (Wk rows 0..255, Wv rows 256..511) ----------------
__global__ void wconv_kernel(const float* __restrict__ Wk, const float* __restrict__ Wv, u16* __restrict__ wkv)
{
  int i = blockIdx.x * 256 + threadIdx.x;   // 65536
  wkv[i] = f2bf(Wk[i]);
  wkv[i + 65536] = f2bf(Wv[i]);
}

// ---------------- fused LN + K/V projection GEMM (bf16 MFMA) ----------------
// block: 512 thr (8 waves, 2x4); tile 128 rows x 256 cols; BK=32; grid.y selects K or V weights.
__global__ __launch_bounds__(512) void gemm_kv(
    const float* __restrict__ x, const float2* __restrict__ murstd,
    const u16* __restrict__ wkv, const float* __restrict__ lng, const float* __restrict__ lnb,
    u16* __restrict__ kbuf, u16* __restrict__ vbuf)
{
  __shared__ __align__(16) u16 As[128 * 40];
  __shared__ __align__(16) u16 Bs[256 * 40];
  const int t = threadIdx.x;
  const int brow = blockIdx.x * 128;
  const int cg = blockIdx.y;                 // 0 -> K, 1 -> V
  const int lane = t & 63, wid = t >> 6;
  const int wr = wid >> 2, wc = wid & 3;     // wave grid 2 x 4
  const int fr = lane & 15, fq = lane >> 4;

  f32x4 acc[4][4];
  #pragma unroll
  for (int i = 0; i < 4; ++i)
    #pragma unroll
    for (int j = 0; j < 4; ++j) { f32x4 z = {0.f,0.f,0.f,0.f}; acc[i][j] = z; }

  for (int kk = 0; kk < 256; kk += 32) {
    // stage A: 128 rows x 32 c, LN fused, fp32 -> bf16
    #pragma unroll
    for (int p = 0; p < 2; ++p) {
      int q = t + p * 512;
      int row = q >> 3;
      int c4 = (q & 7) * 4;
      int grow = brow + row;
      f32x4 xv = *(const f32x4*)&x[(size_t)grow * 256 + kk + c4];
      float2 mr = murstd[grow];
      f32x4 gv = *(const f32x4*)&lng[kk + c4];
      f32x4 bv = *(const f32x4*)&lnb[kk + c4];
      u16 h0 = f2bf((xv.x - mr.x) * mr.y * gv.x + bv.x);
      u16 h1 = f2bf((xv.y - mr.x) * mr.y * gv.y + bv.y);
      u16 h2 = f2bf((xv.z - mr.x) * mr.y * gv.z + bv.z);
      u16 h3 = f2bf((xv.w - mr.x) * mr.y * gv.w + bv.w);
      uint2 pk;
      pk.x = (unsigned)h0 | ((unsigned)h1 << 16);
      pk.y = (unsigned)h2 | ((unsigned)h3 << 16);
      *(uint2*)&As[row * 40 + c4] = pk;
    }
    // stage B: 256 cols x 32 k (Bs[col][k] = Wkv[col][k], already B^T-friendly)
    #pragma unroll
    for (int p = 0; p < 2; ++p) {
      int q = t + p * 512;
      int col = q >> 2;
      int k8 = (q & 3) * 8;
      *(s16x8*)&Bs[col * 40 + k8] = *(const s16x8*)&wkv[(cg * 256 + col) * 256 + kk + k8];
    }
    __syncthreads();
    s16x8 af[4], bfr[4];
    #pragma unroll
    for (int i = 0; i < 4; ++i) af[i]  = *(const s16x8*)&As[(wr * 64 + i * 16 + fr) * 40 + fq * 8];
    #pragma unroll
    for (int j = 0; j < 4; ++j) bfr[j] = *(const s16x8*)&Bs[(wc * 64 + j * 16 + fr) * 40 + fq * 8];
    #pragma unroll
    for (int i = 0; i < 4; ++i)
      #pragma unroll
      for (int j = 0; j < 4; ++j)
        acc[i][j] = __builtin_amdgcn_mfma_f32_16x16x32_bf16(af[i], bfr[j], acc[i][j], 0, 0, 0);
    __syncthreads();
  }
  u16* outb = (cg == 0) ? kbuf : vbuf;
  #pragma unroll
  for (int i = 0; i < 4; ++i)
    #pragma unroll
    for (int j = 0; j < 4; ++j)
      #pragma unroll
      for (int r = 0; r < 4; ++r) {
        int row = brow + wr * 64 + i * 16 + fq * 4 + r;   // C/D: row=(lane>>4)*4+reg
        int col = wc * 64 + j * 16 + fr;                  //      col=lane&15
        outb[(size_t)row * 256 + col] = f2bf(acc[i][j][r]);
      }
}

// ---------------- block stats helper (256 threads) ----------------
__device__ __forceinline__ void block_stats_256(float v, float* scr, float& mu, float& rstd)
{
  float s = v, sq = v * v;
  #pragma unroll
  for (int m = 1; m < 64; m <<= 1) { s += __shfl_xor(s, m, 64); sq += __shfl_xor(sq, m, 64); }
  int wid = threadIdx.x >> 6;
  if ((threadIdx.x & 63) == 0) { scr[wid * 2] = s; scr[wid * 2 + 1] = sq; }
  __syncthreads();
  float ts = scr[0] + scr[2] + scr[4] + scr[6];
  float tq = scr[1] + scr[3] + scr[5] + scr[7];
  __syncthreads();
  mu = ts * (1.0f / 256.0f);
  float var = tq * (1.0f / 256.0f) - mu * mu;
  rstd = rsqrtf(var + 1e-3f);
}

// ---------------- slot LN + q projection (SCALE folded) ----------------
__global__ __launch_bounds__(256) void qproj_kernel(const float* __restrict__ slots, const float* __restrict__ Wq,
    const float* __restrict__ g, const float* __restrict__ be, float* __restrict__ gq)
{
  __shared__ __align__(16) float sl[256];
  __shared__ float scr[8];
  int bs = blockIdx.x, t = threadIdx.x;
  float x = slots[bs * 256 + t];
  float mu, rstd;
  block_stats_256(x, scr, mu, rstd);
  sl[t] = (x - mu) * rstd * g[t] + be[t];
  __syncthreads();
  const f32x4* wr = (const f32x4*)&Wq[t * 256];
  const f32x4* slv = (const f32x4*)sl;
  float a = 0.f;
  #pragma unroll 8
  for (int p = 0; p < 64; ++p) {
    f32x4 u4 = slv[p]; f32x4 w4 = wr[p];
    a += u4.x * w4.x + u4.y * w4.y + u4.z * w4.z + u4.w * w4.w;
  }
  gq[bs * 256 + t] = a * 0.0625f;   // SCALE = 1/16
}

__global__ void zero_kernel(float* __restrict__ p, int n)
{
  int i = blockIdx.x * 256 + threadIdx.x;
  if (i < n) p[i] = 0.f;
}

// ---------------- fused dots + softmax(over S) + denom + U partial ----------------
// grid: (8 chunks, 64 batches), block 256. Each block: 512 n-rows in 8 tiles of 64.
__global__ __launch_bounds__(256) void attn_kernel(
    const u16* __restrict__ kbuf, const u16* __restrict__ vbuf,
    const float* __restrict__ gq, float* __restrict__ gU, float* __restrict__ gdenom)
{
  __shared__ __align__(16) u16 tile[64 * 264];
  __shared__ __align__(16) float qs[8 * 260];
  __shared__ float wl[8 * 72];
  __shared__ float red[256];
  const int b = blockIdx.y, chunk = blockIdx.x;
  const int t = threadIdx.x;
  #pragma unroll
  for (int p = 0; p < 8; ++p) {
    int i = t + p * 256;
    qs[(i >> 8) * 260 + (i & 255)] = gq[b * 2048 + i];
  }
  const int s = t & 7, r0 = t >> 3;           // dots mapping
  const int su = t >> 5, d8 = (t & 31) * 8;   // U-update mapping
  float denom_part = 0.f;
  float u[8];
  #pragma unroll
  for (int j = 0; j < 8; ++j) u[j] = 0.f;

  for (int ti = 0; ti < 8; ++ti) {
    const int n0 = chunk * 512 + ti * 64;
    const size_t gbase = ((size_t)b * 4096 + n0) * 256;
    __syncthreads();                      // prior tile fully consumed (also covers qs on ti=0)
    #pragma unroll
    for (int p = 0; p < 8; ++p) {
      int q = t + p * 256;
      int row = q >> 5, c8 = (q & 31) * 8;
      *(s16x8*)&tile[row * 264 + c8] = *(const s16x8*)&kbuf[gbase + row * 256 + c8];
    }
    __syncthreads();
    float dot0 = 0.f, dot1 = 0.f;
    #pragma unroll 4
    for (int p = 0; p < 32; ++p) {
      s16x8 k0 = *(const s16x8*)&tile[r0 * 264 + p * 8];
      s16x8 k1 = *(const s16x8*)&tile[(r0 + 32) * 264 + p * 8];
      f32x4 qa = *(const f32x4*)&qs[s * 260 + p * 8];
      f32x4 qb = *(const f32x4*)&qs[s * 260 + p * 8 + 4];
      dot0 += qa.x * bf2f((u16)k0[0]) + qa.y * bf2f((u16)k0[1]) + qa.z * bf2f((u16)k0[2]) + qa.w * bf2f((u16)k0[3])
            + qb.x * bf2f((u16)k0[4]) + qb.y * bf2f((u16)k0[5]) + qb.z * bf2f((u16)k0[6]) + qb.w * bf2f((u16)k0[7]);
      dot1 += qa.x * bf2f((u16)k1[0]) + qa.y * bf2f((u16)k1[1]) + qa.z * bf2f((u16)k1[2]) + qa.w * bf2f((u16)k1[3])
            + qb.x * bf2f((u16)k1[4]) + qb.y * bf2f((u16)k1[5]) + qb.z * bf2f((u16)k1[6]) + qb.w * bf2f((u16)k1[7]);
    }
    // softmax across slot dim: the 8 consecutive lanes (t&7) hold s=0..7 for the same n-row
    float m0 = dot0, m1 = dot1;
    #pragma unroll
    for (int msk = 1; msk < 8; msk <<= 1) {
      m0 = fmaxf(m0, __shfl_xor(m0, msk, 64));
      m1 = fmaxf(m1, __shfl_xor(m1, msk, 64));
    }
    float e0 = expf(dot0 - m0), e1 = expf(dot1 - m1);
    float q0 = e0, q1 = e1;
    #pragma unroll
    for (int msk = 1; msk < 8; msk <<= 1) {
      q0 += __shfl_xor(q0, msk, 64);
      q1 += __shfl_xor(q1, msk, 64);
    }
    float w0 = e0 / q0 + 1e-8f;
    float w1 = e1 / q1 + 1e-8f;
    denom_part += w0 + w1;
    wl[s * 72 + r0] = w0;
    wl[s * 72 + r0 + 32] = w1;
    __syncthreads();                      // k-tile reads done, wl written
    #pragma unroll
    for (int p = 0; p < 8; ++p) {
      int q = t + p * 256;
      int row = q >> 5, c8 = (q & 31) * 8;
      *(s16x8*)&tile[row * 264 + c8] = *(const s16x8*)&vbuf[gbase + row * 256 + c8];
    }
    __syncthreads();
    #pragma unroll 4
    for (int r = 0; r < 64; ++r) {
      float wv = wl[su * 72 + r];
      s16x8 vv = *(const s16x8*)&tile[r * 264 + d8];
      u[0] += wv * bf2f((u16)vv[0]); u[1] += wv * bf2f((u16)vv[1]);
      u[2] += wv * bf2f((u16)vv[2]); u[3] += wv * bf2f((u16)vv[3]);
      u[4] += wv * bf2f((u16)vv[4]); u[5] += wv * bf2f((u16)vv[5]);
      u[6] += wv * bf2f((u16)vv[6]); u[7] += wv * bf2f((u16)vv[7]);
    }
  }
  red[t] = denom_part;
  __syncthreads();
  if (t < 8) {
    float sm = 0.f;
    for (int i = 0; i < 32; ++i) sm += red[i * 8 + t];
    atomicAdd(&gdenom[b * 8 + t], sm);
  }
  #pragma unroll
  for (int j = 0; j < 8; ++j)
    atomicAdd(&gU[(size_t)(b * 8 + su) * 256 + d8 + j], u[j]);
}

// ---------------- updates/denom + GRU + LN + MLP residual ----------------
__global__ __launch_bounds__(256) void update_kernel(
    const float* __restrict__ gU, const float* __restrict__ gdenom,
    float* __restrict__ slots,
    const float* __restrict__ W_ih, const float* __restrict__ W_hh,
    const float* __restrict__ b_ih, const float* __restrict__ b_hh,
    const float* __restrict__ W1, const float* __restrict__ b1,
    const float* __restrict__ W2, const float* __restrict__ b2,
    const float* __restrict__ lng, const float* __restrict__ lnb,
    float* __restrict__ out, int last)
{
  __shared__ __align__(16) float us[256];
  __shared__ __align__(16) float sp[256];
  __shared__ __align__(16) float pl[256];
  __shared__ __align__(16) float h1l[512];
  __shared__ float scr[8];
  int b = blockIdx.x, t = threadIdx.x;
  for (int s = 0; s < 8; ++s) {
    int base = (b * 8 + s) * 256;
    float dnm = gdenom[b * 8 + s];
    float uv = gU[base + t] / dnm;
    float spv = slots[base + t];
    us[t] = uv; sp[t] = spv;
    __syncthreads();
    const f32x4* usv = (const f32x4*)us;
    const f32x4* spv4 = (const f32x4*)sp;
    float gx[3], gh[3];
    #pragma unroll
    for (int gi = 0; gi < 3; ++gi) {
      int j = t + gi * 256;
      const f32x4* wi = (const f32x4*)&W_ih[j * 256];
      const f32x4* wh = (const f32x4*)&W_hh[j * 256];
      float ax = 0.f, ah = 0.f;
      #pragma unroll 4
      for (int p = 0; p < 64; ++p) {
        f32x4 u4 = usv[p], s4 = spv4[p];
        f32x4 a4 = wi[p], h4 = wh[p];
        ax += u4.x * a4.x + u4.y * a4.y + u4.z * a4.z + u4.w * a4.w;
        ah += s4.x * h4.x + s4.y * h4.y + s4.z * h4.z + s4.w * h4.w;
      }
      gx[gi] = ax + b_ih[j];
      gh[gi] = ah + b_hh[j];
    }
    float r = 1.f / (1.f + expf(-(gx[0] + gh[0])));
    float z = 1.f / (1.f + expf(-(gx[1] + gh[1])));
    float nn = tanhf(gx[2] + r * gh[2]);
    float news = (1.f - z) * nn + z * spv;
    float mu, rstd;
    block_stats_256(news, scr, mu, rstd);
    pl[t] = (news - mu) * rstd * lng[t] + lnb[t];
    __syncthreads();
    const f32x4* plv = (const f32x4*)pl;
    float h1v0, h1v1;
    {
      const f32x4* w1a = (const f32x4*)&W1[t * 256];
      const f32x4* w1b = (const f32x4*)&W1[(t + 256) * 256];
      float a0 = 0.f, a1 = 0.f;
      #pragma unroll 4
      for (int p = 0; p < 64; ++p) {
        f32x4 pv = plv[p];
        f32x4 wa = w1a[p], wb = w1b[p];
        a0 += pv.x * wa.x + pv.y * wa.y + pv.z * wa.z + pv.w * wa.w;
        a1 += pv.x * wb.x + pv.y * wb.y + pv.z * wb.z + pv.w * wb.w;
      }
      h1v0 = fmaxf(a0 + b1[t], 0.f);
      h1v1 = fmaxf(a1 + b1[t + 256], 0.f);
    }
    h1l[t] = h1v0; h1l[t + 256] = h1v1;
    __syncthreads();
    const f32x4* h1v4 = (const f32x4*)h1l;
    const f32x4* w2r = (const f32x4*)&W2[t * 512];
    float o = 0.f;
    #pragma unroll 4
    for (int p = 0; p < 128; ++p) {
      f32x4 h4 = h1v4[p], w4 = w2r[p];
      o += h4.x * w4.x + h4.y * w4.y + h4.z * w4.z + h4.w * w4.w;
    }
    o += news + b2[t];
    slots[base + t] = o;
    if (last) out[base + t] = o;
    __syncthreads();
  }
}

extern "C" void kernel_launch(void* const* d_in, const int* in_sizes, int n_in,
                              void* d_out, int out_size, void* d_ws, size_t ws_size,
                              hipStream_t stream) {
  const float* inputs   = (const float*)d_in[0];
  const float* noise    = (const float*)d_in[1];
  const float* slots_mu = (const float*)d_in[2];
  const float* slots_ls = (const float*)d_in[3];
  const float* Wq   = (const float*)d_in[4];
  const float* Wk   = (const float*)d_in[5];
  const float* Wv   = (const float*)d_in[6];
  const float* W_ih = (const float*)d_in[7];
  const float* W_hh = (const float*)d_in[8];
  const float* b_ih = (const float*)d_in[9];
  const float* b_hh = (const float*)d_in[10];
  const float* W1   = (const float*)d_in[11];
  const float* b1   = (const float*)d_in[12];
  const float* W2   = (const float*)d_in[13];
  const float* b2   = (const float*)d_in[14];
  const float* ln_in_g = (const float*)d_in[15];
  const float* ln_in_b = (const float*)d_in[16];
  const float* ln_s_g  = (const float*)d_in[17];
  const float* ln_s_b  = (const float*)d_in[18];
  const float* ln_ff_g = (const float*)d_in[19];
  const float* ln_ff_b = (const float*)d_in[20];
  float* out = (float*)d_out;

  char* w = (char*)d_ws;
  u16* kbuf = (u16*)w;          w += (size_t)GM * 256 * 2;   // 128 MB
  u16* vbuf = (u16*)w;          w += (size_t)GM * 256 * 2;   // 128 MB
  u16* wkv = (u16*)w;           w += (size_t)512 * 256 * 2;  // 256 KB
  float2* murstd = (float2*)w;  w += (size_t)GM * 8;         // 2 MB
  float* slots = (float*)w;     w += (size_t)131072 * 4;
  float* gq = (float*)w;        w += (size_t)131072 * 4;
  float* gU = (float*)w;        w += (size_t)131072 * 4;
  float* gdenom = (float*)w;    w += (size_t)512 * 4;        // contiguous after gU

  init_slots_kernel<<<512, 256, 0, stream>>>(noise, slots_mu, slots_ls, slots);
  ln_stats_kernel<<<GM / 4, 256, 0, stream>>>(inputs, murstd);
  wconv_kernel<<<256, 256, 0, stream>>>(Wk, Wv, wkv);
  gemm_kv<<<dim3(GM / 128, 2), 512, 0, stream>>>(inputs, murstd, wkv, ln_in_g, ln_in_b, kbuf, vbuf);

  for (int it = 0; it < 3; ++it) {
    qproj_kernel<<<512, 256, 0, stream>>>(slots, Wq, ln_s_g, ln_s_b, gq);
    zero_kernel<<<(131584 + 255) / 256, 256, 0, stream>>>(gU, 131584);  // gU + gdenom
    attn_kernel<<<dim3(8, 64), 256, 0, stream>>>(kbuf, vbuf, gq, gU, gdenom);
    update_kernel<<<64, 256, 0, stream>>>(gU, gdenom, slots, W_ih, W_hh, b_ih, b_hh,
                                          W1, b1, W2, b2, ln_ff_g, ln_ff_b, out, it == 2);
  }
}

// Round 2
// 860.149 us; speedup vs baseline: 2.6859x; 2.6859x over previous
//
#include <hip/hip_runtime.h>

typedef unsigned short u16;
typedef __attribute__((ext_vector_type(4))) float f32x4;
typedef __attribute__((ext_vector_type(8))) short s16x8;

#define GM 262144   // B*N rows
#define GB 64
#define GN 4096
#define GC 256
#define GD 256
#define GS 8
#define GH 512

__device__ __forceinline__ float bf2f(u16 u) {
  union { unsigned int i; float f; } c; c.i = ((unsigned int)u) << 16; return c.f;
}
__device__ __forceinline__ u16 f2bf(float f) {
  union { float f; unsigned int i; } c; c.f = f;
  unsigned int x = c.i;
  unsigned int r = x + 0x7FFFu + ((x >> 16) & 1u);
  return (u16)(r >> 16);
}
__device__ __forceinline__ float dot4(f32x4 a, f32x4 b) {
  return a.x*b.x + a.y*b.y + a.z*b.z + a.w*b.w;
}

// ---------------- slots init: mu + exp(log_sigma)*noise ----------------
__global__ void init_slots_kernel(const float* __restrict__ noise, const float* __restrict__ smu,
                                  const float* __restrict__ sls, float* __restrict__ slots)
{
  int i = blockIdx.x * 256 + threadIdx.x;   // 131072 total
  int d = i & 255;
  slots[i] = smu[d] + expf(sls[d]) * noise[i];
}

// ---------------- per-row LN stats of inputs ----------------
__global__ __launch_bounds__(256) void ln_stats_kernel(const float* __restrict__ x, float2* __restrict__ murstd)
{
  int row = blockIdx.x * 4 + (threadIdx.x >> 6);
  int lane = threadIdx.x & 63;
  f32x4 v = *(const f32x4*)&x[(size_t)row * 256 + lane * 4];
  float s = v.x + v.y + v.z + v.w;
  float sq = v.x*v.x + v.y*v.y + v.z*v.z + v.w*v.w;
  #pragma unroll
  for (int m = 1; m < 64; m <<= 1) { s += __shfl_xor(s, m, 64); sq += __shfl_xor(sq, m, 64); }
  if (lane == 0) {
    float mu = s * (1.f/256.f);
    float var = sq * (1.f/256.f) - mu*mu;
    murstd[row] = make_float2(mu, rsqrtf(var + 1e-3f));
  }
}

// ---------------- weight convert fp32->bf16 (Wk rows 0..255, Wv rows 256..511) ----------------
__global__ void wconv_kernel(const float* __restrict__ Wk, const float* __restrict__ Wv, u16* __restrict__ wkv)
{
  int i = blockIdx.x * 256 + threadIdx.x;   // 65536
  wkv[i] = f2bf(Wk[i]);
  wkv[i + 65536] = f2bf(Wv[i]);
}

// ---------------- fused LN + K/V projection GEMM (bf16 MFMA) ----------------
// block: 512 thr (8 waves, 2x4); tile 128 rows x 256 cols; BK=32; grid.y selects K or V weights.
__global__ __launch_bounds__(512) void gemm_kv(
    const float* __restrict__ x, const float2* __restrict__ murstd,
    const u16* __restrict__ wkv, const float* __restrict__ lng, const float* __restrict__ lnb,
    u16* __restrict__ kbuf, u16* __restrict__ vbuf)
{
  __shared__ __align__(16) u16 As[128 * 40];
  __shared__ __align__(16) u16 Bs[256 * 40];
  const int t = threadIdx.x;
  const int brow = blockIdx.x * 128;
  const int cg = blockIdx.y;                 // 0 -> K, 1 -> V
  const int lane = t & 63, wid = t >> 6;
  const int wr = wid >> 2, wc = wid & 3;     // wave grid 2 x 4
  const int fr = lane & 15, fq = lane >> 4;

  f32x4 acc[4][4];
  #pragma unroll
  for (int i = 0; i < 4; ++i)
    #pragma unroll
    for (int j = 0; j < 4; ++j) { f32x4 z = {0.f,0.f,0.f,0.f}; acc[i][j] = z; }

  for (int kk = 0; kk < 256; kk += 32) {
    // stage A: 128 rows x 32 c, LN fused, fp32 -> bf16
    #pragma unroll
    for (int p = 0; p < 2; ++p) {
      int q = t + p * 512;
      int row = q >> 3;
      int c4 = (q & 7) * 4;
      int grow = brow + row;
      f32x4 xv = *(const f32x4*)&x[(size_t)grow * 256 + kk + c4];
      float2 mr = murstd[grow];
      f32x4 gv = *(const f32x4*)&lng[kk + c4];
      f32x4 bv = *(const f32x4*)&lnb[kk + c4];
      u16 h0 = f2bf((xv.x - mr.x) * mr.y * gv.x + bv.x);
      u16 h1 = f2bf((xv.y - mr.x) * mr.y * gv.y + bv.y);
      u16 h2 = f2bf((xv.z - mr.x) * mr.y * gv.z + bv.z);
      u16 h3 = f2bf((xv.w - mr.x) * mr.y * gv.w + bv.w);
      uint2 pk;
      pk.x = (unsigned)h0 | ((unsigned)h1 << 16);
      pk.y = (unsigned)h2 | ((unsigned)h3 << 16);
      *(uint2*)&As[row * 40 + c4] = pk;
    }
    // stage B: 256 cols x 32 k (Bs[col][k] = Wkv[col][k], already B^T-friendly)
    #pragma unroll
    for (int p = 0; p < 2; ++p) {
      int q = t + p * 512;
      int col = q >> 2;
      int k8 = (q & 3) * 8;
      *(s16x8*)&Bs[col * 40 + k8] = *(const s16x8*)&wkv[(cg * 256 + col) * 256 + kk + k8];
    }
    __syncthreads();
    s16x8 af[4], bfr[4];
    #pragma unroll
    for (int i = 0; i < 4; ++i) af[i]  = *(const s16x8*)&As[(wr * 64 + i * 16 + fr) * 40 + fq * 8];
    #pragma unroll
    for (int j = 0; j < 4; ++j) bfr[j] = *(const s16x8*)&Bs[(wc * 64 + j * 16 + fr) * 40 + fq * 8];
    #pragma unroll
    for (int i = 0; i < 4; ++i)
      #pragma unroll
      for (int j = 0; j < 4; ++j)
        acc[i][j] = __builtin_amdgcn_mfma_f32_16x16x32_bf16(af[i], bfr[j], acc[i][j], 0, 0, 0);
    __syncthreads();
  }
  u16* outb = (cg == 0) ? kbuf : vbuf;
  #pragma unroll
  for (int i = 0; i < 4; ++i)
    #pragma unroll
    for (int j = 0; j < 4; ++j)
      #pragma unroll
      for (int r = 0; r < 4; ++r) {
        int row = brow + wr * 64 + i * 16 + fq * 4 + r;   // C/D: row=(lane>>4)*4+reg
        int col = wc * 64 + j * 16 + fr;                  //      col=lane&15
        outb[(size_t)row * 256 + col] = f2bf(acc[i][j][r]);
      }
}

// ---------------- block stats helper (256 threads) ----------------
__device__ __forceinline__ void block_stats_256(float v, float* scr, float& mu, float& rstd)
{
  float s = v, sq = v * v;
  #pragma unroll
  for (int m = 1; m < 64; m <<= 1) { s += __shfl_xor(s, m, 64); sq += __shfl_xor(sq, m, 64); }
  int wid = threadIdx.x >> 6;
  if ((threadIdx.x & 63) == 0) { scr[wid * 2] = s; scr[wid * 2 + 1] = sq; }
  __syncthreads();
  float ts = scr[0] + scr[2] + scr[4] + scr[6];
  float tq = scr[1] + scr[3] + scr[5] + scr[7];
  __syncthreads();
  mu = ts * (1.0f / 256.0f);
  float var = tq * (1.0f / 256.0f) - mu * mu;
  rstd = rsqrtf(var + 1e-3f);
}

// ---------------- slot LN + q projection (SCALE folded) ----------------
__global__ __launch_bounds__(256) void qproj_kernel(const float* __restrict__ slots, const float* __restrict__ Wq,
    const float* __restrict__ g, const float* __restrict__ be, float* __restrict__ gq)
{
  __shared__ __align__(16) float sl[256];
  __shared__ float scr[8];
  int bs = blockIdx.x, t = threadIdx.x;
  float x = slots[bs * 256 + t];
  float mu, rstd;
  block_stats_256(x, scr, mu, rstd);
  sl[t] = (x - mu) * rstd * g[t] + be[t];
  __syncthreads();
  const f32x4* wr = (const f32x4*)&Wq[t * 256];
  const f32x4* slv = (const f32x4*)sl;
  float a = 0.f;
  #pragma unroll 8
  for (int p = 0; p < 64; ++p) {
    f32x4 u4 = slv[p]; f32x4 w4 = wr[p];
    a += u4.x * w4.x + u4.y * w4.y + u4.z * w4.z + u4.w * w4.w;
  }
  gq[bs * 256 + t] = a * 0.0625f;   // SCALE = 1/16
}

__global__ void zero_kernel(float* __restrict__ p, int n)
{
  int i = blockIdx.x * 256 + threadIdx.x;
  if (i < n) p[i] = 0.f;
}

// ---------------- fused dots + softmax(over S) + denom + U partial ----------------
// grid: (8 chunks, 64 batches), block 256. Each block: 512 n-rows in 8 tiles of 64.
__global__ __launch_bounds__(256) void attn_kernel(
    const u16* __restrict__ kbuf, const u16* __restrict__ vbuf,
    const float* __restrict__ gq, float* __restrict__ gU, float* __restrict__ gdenom)
{
  __shared__ __align__(16) u16 tile[64 * 264];
  __shared__ __align__(16) float qs[8 * 260];
  __shared__ float wl[8 * 72];
  __shared__ float red[256];
  const int b = blockIdx.y, chunk = blockIdx.x;
  const int t = threadIdx.x;
  #pragma unroll
  for (int p = 0; p < 8; ++p) {
    int i = t + p * 256;
    qs[(i >> 8) * 260 + (i & 255)] = gq[b * 2048 + i];
  }
  const int s = t & 7, r0 = t >> 3;           // dots mapping
  const int su = t >> 5, d8 = (t & 31) * 8;   // U-update mapping
  float denom_part = 0.f;
  float u[8];
  #pragma unroll
  for (int j = 0; j < 8; ++j) u[j] = 0.f;

  for (int ti = 0; ti < 8; ++ti) {
    const int n0 = chunk * 512 + ti * 64;
    const size_t gbase = ((size_t)b * 4096 + n0) * 256;
    __syncthreads();                      // prior tile fully consumed (also covers qs on ti=0)
    #pragma unroll
    for (int p = 0; p < 8; ++p) {
      int q = t + p * 256;
      int row = q >> 5, c8 = (q & 31) * 8;
      *(s16x8*)&tile[row * 264 + c8] = *(const s16x8*)&kbuf[gbase + row * 256 + c8];
    }
    __syncthreads();
    float dot0 = 0.f, dot1 = 0.f;
    #pragma unroll 4
    for (int p = 0; p < 32; ++p) {
      s16x8 k0 = *(const s16x8*)&tile[r0 * 264 + p * 8];
      s16x8 k1 = *(const s16x8*)&tile[(r0 + 32) * 264 + p * 8];
      f32x4 qa = *(const f32x4*)&qs[s * 260 + p * 8];
      f32x4 qb = *(const f32x4*)&qs[s * 260 + p * 8 + 4];
      dot0 += qa.x * bf2f((u16)k0[0]) + qa.y * bf2f((u16)k0[1]) + qa.z * bf2f((u16)k0[2]) + qa.w * bf2f((u16)k0[3])
            + qb.x * bf2f((u16)k0[4]) + qb.y * bf2f((u16)k0[5]) + qb.z * bf2f((u16)k0[6]) + qb.w * bf2f((u16)k0[7]);
      dot1 += qa.x * bf2f((u16)k1[0]) + qa.y * bf2f((u16)k1[1]) + qa.z * bf2f((u16)k1[2]) + qa.w * bf2f((u16)k1[3])
            + qb.x * bf2f((u16)k1[4]) + qb.y * bf2f((u16)k1[5]) + qb.z * bf2f((u16)k1[6]) + qb.w * bf2f((u16)k1[7]);
    }
    // softmax across slot dim: the 8 consecutive lanes (t&7) hold s=0..7 for the same n-row
    float m0 = dot0, m1 = dot1;
    #pragma unroll
    for (int msk = 1; msk < 8; msk <<= 1) {
      m0 = fmaxf(m0, __shfl_xor(m0, msk, 64));
      m1 = fmaxf(m1, __shfl_xor(m1, msk, 64));
    }
    float e0 = expf(dot0 - m0), e1 = expf(dot1 - m1);
    float q0 = e0, q1 = e1;
    #pragma unroll
    for (int msk = 1; msk < 8; msk <<= 1) {
      q0 += __shfl_xor(q0, msk, 64);
      q1 += __shfl_xor(q1, msk, 64);
    }
    float w0 = e0 / q0 + 1e-8f;
    float w1 = e1 / q1 + 1e-8f;
    denom_part += w0 + w1;
    wl[s * 72 + r0] = w0;
    wl[s * 72 + r0 + 32] = w1;
    __syncthreads();                      // k-tile reads done, wl written
    #pragma unroll
    for (int p = 0; p < 8; ++p) {
      int q = t + p * 256;
      int row = q >> 5, c8 = (q & 31) * 8;
      *(s16x8*)&tile[row * 264 + c8] = *(const s16x8*)&vbuf[gbase + row * 256 + c8];
    }
    __syncthreads();
    #pragma unroll 4
    for (int r = 0; r < 64; ++r) {
      float wv = wl[su * 72 + r];
      s16x8 vv = *(const s16x8*)&tile[r * 264 + d8];
      u[0] += wv * bf2f((u16)vv[0]); u[1] += wv * bf2f((u16)vv[1]);
      u[2] += wv * bf2f((u16)vv[2]); u[3] += wv * bf2f((u16)vv[3]);
      u[4] += wv * bf2f((u16)vv[4]); u[5] += wv * bf2f((u16)vv[5]);
      u[6] += wv * bf2f((u16)vv[6]); u[7] += wv * bf2f((u16)vv[7]);
    }
  }
  red[t] = denom_part;
  __syncthreads();
  if (t < 8) {
    float sm = 0.f;
    for (int i = 0; i < 32; ++i) sm += red[i * 8 + t];
    atomicAdd(&gdenom[b * 8 + t], sm);
  }
  #pragma unroll
  for (int j = 0; j < 8; ++j)
    atomicAdd(&gU[(size_t)(b * 8 + su) * 256 + d8 + j], u[j]);
}

// ---------------- updates/denom + GRU + LN + MLP residual ----------------
// grid: 128 blocks; block (bid>>1) = batch, (bid&1)*4 = first of 4 slots handled concurrently.
// Thread t owns weight rows {t, t+256, t+512} (gates), {t, t+256} (W1), {t} (W2);
// accumulates all 4 slots simultaneously (k-outer loop, slot vecs broadcast from LDS).
__global__ __launch_bounds__(256) void update_kernel(
    const float* __restrict__ gU, const float* __restrict__ gdenom,
    float* __restrict__ slots,
    const float* __restrict__ W_ih, const float* __restrict__ W_hh,
    const float* __restrict__ b_ih, const float* __restrict__ b_hh,
    const float* __restrict__ W1, const float* __restrict__ b1,
    const float* __restrict__ W2, const float* __restrict__ b2,
    const float* __restrict__ lng, const float* __restrict__ lnb,
    float* __restrict__ out, int last)
{
  __shared__ __align__(16) float us[1024];
  __shared__ __align__(16) float sp[1024];
  __shared__ __align__(16) float nl[1024];
  __shared__ __align__(16) float pl[1024];
  __shared__ __align__(16) float h1[2048];
  __shared__ float scr[8];
  const int bid = blockIdx.x;
  const int b = bid >> 1, s0 = (bid & 1) * 4;
  const int t = threadIdx.x;

  float spv[4];
  #pragma unroll
  for (int s = 0; s < 4; ++s) {
    int gsl = b * 8 + s0 + s;
    float dnm = gdenom[gsl];
    us[s * 256 + t] = gU[gsl * 256 + t] / dnm;
    float v = slots[gsl * 256 + t];
    sp[s * 256 + t] = v;
    spv[s] = v;
  }
  __syncthreads();

  // ---- GRU gates: thread t computes rows t, t+256, t+512 of gx and gh for 4 slots ----
  const f32x4* usv = (const f32x4*)us;
  const f32x4* spv4 = (const f32x4*)sp;
  float ax[3][4], ah[3][4];
  #pragma unroll
  for (int gi = 0; gi < 3; ++gi)
    #pragma unroll
    for (int s = 0; s < 4; ++s) { ax[gi][s] = 0.f; ah[gi][s] = 0.f; }
  #pragma unroll 2
  for (int k = 0; k < 64; ++k) {
    f32x4 wi[3], wh[3];
    #pragma unroll
    for (int gi = 0; gi < 3; ++gi) {
      wi[gi] = *(const f32x4*)&W_ih[(size_t)(gi * 256 + t) * 256 + k * 4];
      wh[gi] = *(const f32x4*)&W_hh[(size_t)(gi * 256 + t) * 256 + k * 4];
    }
    f32x4 uu[4], ss[4];
    #pragma unroll
    for (int s = 0; s < 4; ++s) { uu[s] = usv[s * 64 + k]; ss[s] = spv4[s * 64 + k]; }
    #pragma unroll
    for (int gi = 0; gi < 3; ++gi)
      #pragma unroll
      for (int s = 0; s < 4; ++s) {
        ax[gi][s] += dot4(wi[gi], uu[s]);
        ah[gi][s] += dot4(wh[gi], ss[s]);
      }
  }
  float bi0 = b_ih[t], bi1 = b_ih[t + 256], bi2 = b_ih[t + 512];
  float bh0 = b_hh[t], bh1 = b_hh[t + 256], bh2 = b_hh[t + 512];
  float news[4];
  #pragma unroll
  for (int s = 0; s < 4; ++s) {
    float r = 1.f / (1.f + expf(-(ax[0][s] + bi0 + ah[0][s] + bh0)));
    float z = 1.f / (1.f + expf(-(ax[1][s] + bi1 + ah[1][s] + bh1)));
    float nn = tanhf(ax[2][s] + bi2 + r * (ah[2][s] + bh2));
    news[s] = (1.f - z) * nn + z * spv[s];
    nl[s * 256 + t] = news[s];
  }
  __syncthreads();

  // ---- LN stats: wave w handles slot w ----
  {
    int wv = t >> 6, ln = t & 63;
    f32x4 v = *(const f32x4*)&nl[wv * 256 + ln * 4];
    float s1 = v.x + v.y + v.z + v.w;
    float s2 = v.x*v.x + v.y*v.y + v.z*v.z + v.w*v.w;
    #pragma unroll
    for (int m = 1; m < 64; m <<= 1) { s1 += __shfl_xor(s1, m, 64); s2 += __shfl_xor(s2, m, 64); }
    if (ln == 0) {
      float mu = s1 * (1.f / 256.f);
      float var = s2 * (1.f / 256.f) - mu * mu;
      scr[wv * 2] = mu;
      scr[wv * 2 + 1] = rsqrtf(var + 1e-3f);
    }
  }
  __syncthreads();
  float lg = lng[t], lb = lnb[t];
  #pragma unroll
  for (int s = 0; s < 4; ++s)
    pl[s * 256 + t] = (news[s] - scr[s * 2]) * scr[s * 2 + 1] * lg + lb;
  __syncthreads();

  // ---- MLP layer 1: thread t computes h1 rows t and t+256 for 4 slots ----
  const f32x4* plv = (const f32x4*)pl;
  {
    float a0[4], a1[4];
    #pragma unroll
    for (int s = 0; s < 4; ++s) { a0[s] = 0.f; a1[s] = 0.f; }
    #pragma unroll 2
    for (int k = 0; k < 64; ++k) {
      f32x4 wa = *(const f32x4*)&W1[(size_t)t * 256 + k * 4];
      f32x4 wb = *(const f32x4*)&W1[(size_t)(t + 256) * 256 + k * 4];
      #pragma unroll
      for (int s = 0; s < 4; ++s) {
        f32x4 pv = plv[s * 64 + k];
        a0[s] += dot4(wa, pv);
        a1[s] += dot4(wb, pv);
      }
    }
    float bb0 = b1[t], bb1 = b1[t + 256];
    #pragma unroll
    for (int s = 0; s < 4; ++s) {
      h1[s * 512 + t] = fmaxf(a0[s] + bb0, 0.f);
      h1[s * 512 + t + 256] = fmaxf(a1[s] + bb1, 0.f);
    }
  }
  __syncthreads();

  // ---- MLP layer 2 + residual ----
  const f32x4* h1v = (const f32x4*)h1;
  float o[4];
  #pragma unroll
  for (int s = 0; s < 4; ++s) o[s] = 0.f;
  #pragma unroll 2
  for (int k = 0; k < 128; ++k) {
    f32x4 w4 = *(const f32x4*)&W2[(size_t)t * 512 + k * 4];
    #pragma unroll
    for (int s = 0; s < 4; ++s)
      o[s] += dot4(w4, h1v[s * 128 + k]);
  }
  float bb2 = b2[t];
  #pragma unroll
  for (int s = 0; s < 4; ++s) {
    int gsl = b * 8 + s0 + s;
    float val = o[s] + news[s] + bb2;
    slots[gsl * 256 + t] = val;
    if (last) out[gsl * 256 + t] = val;
  }
}

extern "C" void kernel_launch(void* const* d_in, const int* in_sizes, int n_in,
                              void* d_out, int out_size, void* d_ws, size_t ws_size,
                              hipStream_t stream) {
  const float* inputs   = (const float*)d_in[0];
  const float* noise    = (const float*)d_in[1];
  const float* slots_mu = (const float*)d_in[2];
  const float* slots_ls = (const float*)d_in[3];
  const float* Wq   = (const float*)d_in[4];
  const float* Wk   = (const float*)d_in[5];
  const float* Wv   = (const float*)d_in[6];
  const float* W_ih = (const float*)d_in[7];
  const float* W_hh = (const float*)d_in[8];
  const float* b_ih = (const float*)d_in[9];
  const float* b_hh = (const float*)d_in[10];
  const float* W1   = (const float*)d_in[11];
  const float* b1   = (const float*)d_in[12];
  const float* W2   = (const float*)d_in[13];
  const float* b2   = (const float*)d_in[14];
  const float* ln_in_g = (const float*)d_in[15];
  const float* ln_in_b = (const float*)d_in[16];
  const float* ln_s_g  = (const float*)d_in[17];
  const float* ln_s_b  = (const float*)d_in[18];
  const float* ln_ff_g = (const float*)d_in[19];
  const float* ln_ff_b = (const float*)d_in[20];
  float* out = (float*)d_out;

  char* w = (char*)d_ws;
  u16* kbuf = (u16*)w;          w += (size_t)GM * 256 * 2;   // 128 MB
  u16* vbuf = (u16*)w;          w += (size_t)GM * 256 * 2;   // 128 MB
  u16* wkv = (u16*)w;           w += (size_t)512 * 256 * 2;  // 256 KB
  float2* murstd = (float2*)w;  w += (size_t)GM * 8;         // 2 MB
  float* slots = (float*)w;     w += (size_t)131072 * 4;
  float* gq = (float*)w;        w += (size_t)131072 * 4;
  float* gU = (float*)w;        w += (size_t)131072 * 4;
  float* gdenom = (float*)w;    w += (size_t)512 * 4;        // contiguous after gU

  init_slots_kernel<<<512, 256, 0, stream>>>(noise, slots_mu, slots_ls, slots);
  ln_stats_kernel<<<GM / 4, 256, 0, stream>>>(inputs, murstd);
  wconv_kernel<<<256, 256, 0, stream>>>(Wk, Wv, wkv);
  gemm_kv<<<dim3(GM / 128, 2), 512, 0, stream>>>(inputs, murstd, wkv, ln_in_g, ln_in_b, kbuf, vbuf);

  for (int it = 0; it < 3; ++it) {
    qproj_kernel<<<512, 256, 0, stream>>>(slots, Wq, ln_s_g, ln_s_b, gq);
    zero_kernel<<<(131584 + 255) / 256, 256, 0, stream>>>(gU, 131584);  // gU + gdenom
    attn_kernel<<<dim3(8, 64), 256, 0, stream>>>(kbuf, vbuf, gq, gU, gdenom);
    update_kernel<<<128, 256, 0, stream>>>(gU, gdenom, slots, W_ih, W_hh, b_ih, b_hh,
                                           W1, b1, W2, b2, ln_ff_g, ln_ff_b, out, it == 2);
  }
}